// Round 21
// baseline (307.529 us; speedup 1.0000x reference)
//
#include <hip/hip_runtime.h>
#include <math.h>

constexpr int B = 8, C = 64, H = 256, W = 256, HWc = H * W, N = 10;

typedef short bf8 __attribute__((ext_vector_type(8)));    // 8 x bf16 (4 VGPR)
typedef float f4  __attribute__((ext_vector_type(4)));    // MFMA accum
typedef unsigned short ushort;

__device__ __forceinline__ ushort f2bf(float f) {
  unsigned u = __builtin_bit_cast(unsigned, f);
  unsigned r = (u + 0x7fffu + ((u >> 16) & 1u)) >> 16;
  return (ushort)r;
}
__device__ __forceinline__ float bf2f(ushort h) {
  unsigned u = ((unsigned)h) << 16;
  return __builtin_bit_cast(float, u);
}

// ---------------- LayerNorm: NCHW fp32 -> NHWC bf16 ----------------
__global__ __launch_bounds__(256) void ln_k(
    const float* __restrict__ x, const float* __restrict__ g,
    const float* __restrict__ bt, ushort* __restrict__ xn) {
  int pix = blockIdx.x * 256 + threadIdx.x;
  int b = blockIdx.y;
  const float* xp = x + (size_t)b * C * HWc + pix;
  float v[64];
  float s = 0.f, s2 = 0.f;
#pragma unroll
  for (int c = 0; c < 64; c++) {
    v[c] = xp[(size_t)c * HWc];
    s += v[c]; s2 += v[c] * v[c];
  }
  float mu = s * (1.f / 64);
  float var = s2 * (1.f / 64) - mu * mu;
  float rstd = rsqrtf(var + 1e-5f);
  ushort* op = xn + ((size_t)b * HWc + pix) * 64;
#pragma unroll
  for (int ch = 0; ch < 8; ch++) {
    union { ushort us[8]; int4 v4; } pk;
#pragma unroll
    for (int j = 0; j < 8; j++) {
      int c = ch * 8 + j;
      pk.us[j] = f2bf((v[c] - mu) * rstd * g[c] + bt[c]);
    }
    *reinterpret_cast<int4*>(op + ch * 8) = pk.v4;
  }
}

// ---------------- weight prep: OIHW fp32 -> MFMA fragment layout bf16 ----------------
__global__ void prep_w(const float* __restrict__ w3, const float* __restrict__ wu,
                       const float* __restrict__ wd, ushort* __restrict__ frags) {
  int idx = blockIdx.x * 256 + threadIdx.x;
  if (idx >= 3 * 4608) return;
  int conv = idx / 4608, r = idx % 4608;
  int s = r >> 8, cf = (r >> 6) & 3, lane = r & 63;
  const float* w = (conv == 0) ? w3 : (conv == 1) ? wu : wd;
  int co = (cf << 4) + (lane & 15);
  int tap = s >> 1;
  ushort* o = frags + conv * 36864 + ((size_t)r) * 8;
#pragma unroll
  for (int j = 0; j < 8; j++) {
    int ci = ((s & 1) << 5) + ((lane >> 4) << 3) + j;
    o[j] = f2bf(w[(co * 64 + ci) * 9 + tap]);
  }
}

// ======== pixel-BAND staging via global_load_lds ========
// R21 fix: stage full 128-B pixel lines (all 64 ch) per band of 10 rows, so
// each NHWC line is fetched from HBM ONCE. (ci-half staging fetched each
// 128-B line twice -> FETCH was 2x ideal, ~176 MB vs 85, since R5.)
// Band 0 = tile rows 0..9 (outputs f=0..7), band 1 = rows 8..17 (f=8..15).
// 180 px * 8 chunks = 1440 lane-slots, padded to 1536 = 6 glls/wave (uniform).
typedef __attribute__((address_space(3))) unsigned lds_u32;
typedef __attribute__((address_space(1))) const unsigned glb_u32;

__device__ __forceinline__ void stage_band(
    char* ldsbuf, const ushort* __restrict__ in, const ushort* __restrict__ zbuf,
    int b, int h0, int w0, int band, int tid) {
  int wave = tid >> 6, lane = tid & 63;
#pragma unroll
  for (int it = 0; it < 6; it++) {
    int idx = it * 256 + wave * 64 + lane;
    int px = idx >> 3, ch = idx & 7;
    int row = px / 18, c = px % 18;
    int gh = h0 - 1 + band * 8 + row, gw = w0 + c - 1;
    int chs = ch ^ ((c >> 1) & 7);                 // pre-swizzled source chunk
    bool ok = (px < 180) && (gh >= 0) && (gh < H) && (gw >= 0) && (gw < W);
    const ushort* src = ok
        ? in + (((size_t)b * H + gh) * W + gw) * 64 + chs * 8
        : zbuf;
    char* dst = ldsbuf + (it * 256 + wave * 64) * 16;   // wave-uniform + lane*16
    __builtin_amdgcn_global_load_lds((glb_u32*)(const void*)src,
                                     (lds_u32*)(void*)dst, 16, 0, 0);
  }
}

// compute one band (8 output rows, full K=576) with PRELOADED weights
// (VMEM-silent compute: keeps the counted vmcnt gate from being drained).
// LDS slot (px, ch) holds global chunk ch^((c>>1)&7); to read global chunk g
// at pixel (row,lc): chunk index = g ^ ((lc>>1)&7).
__device__ __forceinline__ void compute_band(
    const char* lds, const bf8 (&wb)[18], int band,
    int wave, int lm, int lk, f4 (&acc)[16]) {
#pragma unroll
  for (int dx = 0; dx < 3; dx++) {
    int lc = lm + dx;
    int sz = (lc >> 1) & 7;
#pragma unroll
    for (int ch2 = 0; ch2 < 2; ch2++) {
      bf8 a[10];
#pragma unroll
      for (int r = 0; r < 10; r++) {
        int off = ((r * 18 + lc) << 7) + ((((ch2 << 2) + lk) ^ sz) << 4);
        a[r] = *reinterpret_cast<const bf8*>(lds + off);
      }
#pragma unroll
      for (int dy = 0; dy < 3; dy++) {
        int s = ((dy * 3 + dx) << 1) | ch2;
#pragma unroll
        for (int f = 0; f < 8; f++)
          acc[band * 8 + f] =
              __builtin_amdgcn_mfma_f32_16x16x32_bf16(a[f + dy], wb[s], acc[band * 8 + f], 0, 0, 0);
      }
    }
  }
}

// counted-vmcnt gate + raw barrier
#define VM_GATE(NN)                                                       \
  asm volatile("s_waitcnt vmcnt(" #NN ")" ::: "memory");                  \
  __builtin_amdgcn_s_barrier();                                           \
  __builtin_amdgcn_sched_barrier(0);

// block-level per-channel reduce -> one atomic per channel (transposed, conflict-free)
__device__ __forceinline__ void red_at(
    float* ldsf, const float (&a)[8], float* __restrict__ Ssum,
    int b, int tid) {
  __syncthreads();
#pragma unroll
  for (int j = 0; j < 8; j++) ldsf[j * 256 + tid] = a[j];
  __syncthreads();
  if (tid < 64) {
    float s = 0.f;
#pragma unroll
    for (int kk = 0; kk < 32; kk++) s += ldsf[(tid & 7) * 256 + kk * 8 + (tid >> 3)];
    atomicAdd(&Ssum[b * 64 + tid], s);
  }
}

// ---------------- MFMA implicit-GEMM 3x3 conv (band-staged) ----------------
// OM=0: out NHWC bf16 (+GELU), 2-half LDS-transpose epilogue.
// OM=1: out NCHW fp32 + residual, 2-half LDS-transpose epilogue + resid prefetch.
template <int ACT, int OM, int DOST>
__global__ __launch_bounds__(256, 2) void conv_mfma(
    const ushort* __restrict__ in, const ushort* __restrict__ wfrag,
    const float* __restrict__ bias, const float* __restrict__ resid,
    ushort* __restrict__ outb, float* __restrict__ outf,
    float* __restrict__ Ssum, const ushort* __restrict__ zbuf) {
  __shared__ char lds[2 * 24576];  // band buffers; epilogue reuses 32 KB
  char* ldsA = lds;
  char* ldsB = lds + 24576;
  int tid = threadIdx.x;
  int b = blockIdx.z;
  int h0 = blockIdx.y * 16, w0 = blockIdx.x * 16;
  int wave = tid >> 6, lane = tid & 63;
  int lm = lane & 15, lk = lane >> 4;
  const bf8* wf = reinterpret_cast<const bf8*>(wfrag);

  // weights preloaded BEFORE the glls (in-order completion keeps gates clean)
  bf8 wb[18];
#pragma unroll
  for (int s = 0; s < 18; s++) wb[s] = wf[(s * 4 + wave) * 64 + (lk << 4) + lm];

  f4 acc[16];
  {
    float bv = bias[(wave << 4) + lm];
    f4 ini = {bv, bv, bv, bv};
#pragma unroll
    for (int f = 0; f < 16; f++) acc[f] = ini;
  }

  stage_band(ldsA, in, zbuf, b, h0, w0, 0, tid);
  stage_band(ldsB, in, zbuf, b, h0, w0, 1, tid);
  VM_GATE(6)                     // band-0 resident; band-1 still in flight
  compute_band(ldsA, wb, 0, wave, lm, lk, acc);
  VM_GATE(0)                     // band-1 resident
  compute_band(ldsB, wb, 1, wave, lm, lk, acc);

  float* ldsf = reinterpret_cast<float*>(lds);
  if (OM == 0) {
    float s8[8];
    if (DOST) {
#pragma unroll
      for (int j = 0; j < 8; j++) s8[j] = 0.f;
    }
    // 2 halves of 8 pixel-rows: 8*16 px * 64 co * 4B = 32 KB
    for (int h2 = 0; h2 < 2; h2++) {
      __syncthreads();
#pragma unroll
      for (int fr = 0; fr < 8; fr++) {
        int f = h2 * 8 + fr;
        int co = (wave << 4) + lm;
#pragma unroll
        for (int r = 0; r < 4; r++) {
          int p = (lk << 2) + r;
          ldsf[fr * 1024 + p * 64 + (co ^ ((p & 12) << 2))] = acc[f][r];
        }
      }
      __syncthreads();
#pragma unroll
      for (int i = 0; i < 4; i++) {
        int q2 = i * 256 + tid;               // 0..1023
        int co8 = q2 & 7, p = (q2 >> 3) & 15, fr = q2 >> 7;
        int cb = (co8 * 8) ^ ((p & 12) << 2);
        f4 v0 = *reinterpret_cast<f4*>(&ldsf[fr * 1024 + p * 64 + cb]);
        f4 v1 = *reinterpret_cast<f4*>(&ldsf[fr * 1024 + p * 64 + cb + 4]);
        float vv[8] = {v0[0], v0[1], v0[2], v0[3], v1[0], v1[1], v1[2], v1[3]};
        union { ushort us[8]; int4 i4; } pk;
#pragma unroll
        for (int j = 0; j < 8; j++) {
          float v = vv[j];
          if (ACT) v = 0.5f * v * (1.f + erff(v * 0.70710678118654752f));
          if (DOST) s8[j] += v;
          pk.us[j] = f2bf(v);
        }
        *reinterpret_cast<int4*>(
            outb + (((size_t)b * H + h0 + h2 * 8 + fr) * W + w0 + p) * 64 + co8 * 8) = pk.i4;
      }
    }
    if (DOST) red_at(ldsf, s8, Ssum, b, tid);
  } else {
    // NCHW fp32 + residual; 2 halves of 32 co each + phase-local resid prefetch
    for (int h2 = 0; h2 < 2; h2++) {
      __syncthreads();
      if ((wave >> 1) == h2) {
        int co32 = ((wave & 1) << 4) + lm;
#pragma unroll
        for (int f = 0; f < 16; f++) {
          int pxl = (f << 4) + (lk << 2);
          int pxs = pxl ^ ((lm & 7) << 2);
          *reinterpret_cast<f4*>(&ldsf[co32 * 256 + pxs]) = acc[f];
        }
      }
      float4 rv[8];
#pragma unroll
      for (int i = 0; i < 8; i++) {
        int q2 = i * 256 + tid;               // 0..2047
        int chunk = q2 & 63, co32 = q2 >> 6;
        int pq = chunk * 4;
        int co = h2 * 32 + co32;
        size_t o = ((size_t)(b * 64 + co)) * HWc +
                   (size_t)(h0 + (pq >> 4)) * W + w0 + (pq & 15);
        rv[i] = *reinterpret_cast<const float4*>(resid + o);
      }
      __syncthreads();
#pragma unroll
      for (int i = 0; i < 8; i++) {
        int q2 = i * 256 + tid;
        int chunk = q2 & 63, co32 = q2 >> 6;
        int pq = chunk * 4;                          // UNSWIZZLED pixel base
        int pxs = pq ^ ((co32 & 7) << 2);            // swizzled LDS addr
        f4 v = *reinterpret_cast<f4*>(&ldsf[co32 * 256 + pxs]);
        int co = h2 * 32 + co32;
        size_t o = ((size_t)(b * 64 + co)) * HWc +
                   (size_t)(h0 + (pq >> 4)) * W + w0 + (pq & 15);
        float4 ov;
        ov.x = v[0] + rv[i].x; ov.y = v[1] + rv[i].y;
        ov.z = v[2] + rv[i].z; ov.w = v[3] + rv[i].w;
        *reinterpret_cast<float4*>(outf + o) = ov;
      }
    }
  }
}

// ---------------- fused up-conv + channel mix (band-staged) ----------------
__global__ __launch_bounds__(256, 2) void upmix_mfma(
    const ushort* __restrict__ in, const ushort* __restrict__ wfrag,
    const float* __restrict__ bias, const ushort* __restrict__ wmf,
    ushort* __restrict__ out, const ushort* __restrict__ zbuf) {
  __shared__ char ldsS[24576];   // band 0
  __shared__ char ldsX[32768];   // band 1 / xm tile / epilogue
  int tid = threadIdx.x;
  int b = blockIdx.z;
  int h0 = blockIdx.y * 16, w0 = blockIdx.x * 16;
  int wave = tid >> 6, lane = tid & 63;
  int lm = lane & 15, lk = lane >> 4;
  const bf8* wf = reinterpret_cast<const bf8*>(wfrag);

  bf8 wb[18];
#pragma unroll
  for (int s = 0; s < 18; s++) wb[s] = wf[(s * 4 + wave) * 64 + (lk << 4) + lm];
  const bf8* wmb = reinterpret_cast<const bf8*>(wmf + (size_t)b * 4096);
  bf8 wm[2];
#pragma unroll
  for (int s = 0; s < 2; s++) wm[s] = wmb[(s * 4 + wave) * 64 + lane];

  f4 acc[16];
  {
    float bv = bias[(wave << 4) + lm];
    f4 ini = {bv, bv, bv, bv};
#pragma unroll
    for (int f = 0; f < 16; f++) acc[f] = ini;
  }

  stage_band(ldsS, in, zbuf, b, h0, w0, 0, tid);
  stage_band(ldsX, in, zbuf, b, h0, w0, 1, tid);
  VM_GATE(6)
  compute_band(ldsS, wb, 0, wave, lm, lk, acc);
  VM_GATE(0)
  compute_band(ldsX, wb, 1, wave, lm, lk, acc);
  __syncthreads();   // all waves done reading ldsX before scatter overwrites it

  // scatter acc -> xm tile (bf16) in mix staging layout
#pragma unroll
  for (int f = 0; f < 16; f++) {
#pragma unroll
    for (int r = 0; r < 4; r++) {
      int pc = (lk << 2) + r;
      int pix = (f << 4) + pc;
      int off = ((pix << 7) + ((wave << 4) + lm) * 2) ^ ((pc & 7) << 4);
      *reinterpret_cast<ushort*>(ldsX + off) = f2bf(acc[f][r]);
    }
  }
  __syncthreads();

  f4 acc2[16];
#pragma unroll
  for (int f = 0; f < 16; f++) acc2[f] = (f4){0.f, 0.f, 0.f, 0.f};
#pragma unroll
  for (int s = 0; s < 2; s++) {
    int kbyte = ((s << 5) + (lk << 3)) << 1;
#pragma unroll
    for (int f = 0; f < 16; f++) {
      int off = ((((f << 4) + lm) << 7) + kbyte) ^ ((lm & 7) << 4);
      bf8 a = *reinterpret_cast<const bf8*>(ldsX + off);
      acc2[f] = __builtin_amdgcn_mfma_f32_16x16x32_bf16(a, wm[s], acc2[f], 0, 0, 0);
    }
  }

  // epilogue: 2-half transpose via ldsX (32 KB) -> NHWC bf16
  float* ldsf = reinterpret_cast<float*>(ldsX);
  for (int h2 = 0; h2 < 2; h2++) {
    __syncthreads();
#pragma unroll
    for (int fr = 0; fr < 8; fr++) {
      int f = h2 * 8 + fr;
      int co = (wave << 4) + lm;
#pragma unroll
      for (int r = 0; r < 4; r++) {
        int p = (lk << 2) + r;
        ldsf[fr * 1024 + p * 64 + (co ^ ((p & 12) << 2))] = acc2[f][r];
      }
    }
    __syncthreads();
#pragma unroll
    for (int i = 0; i < 4; i++) {
      int q2 = i * 256 + tid;
      int co8 = q2 & 7, p = (q2 >> 3) & 15, fr = q2 >> 7;
      int cb = (co8 * 8) ^ ((p & 12) << 2);
      f4 v0 = *reinterpret_cast<f4*>(&ldsf[fr * 1024 + p * 64 + cb]);
      f4 v1 = *reinterpret_cast<f4*>(&ldsf[fr * 1024 + p * 64 + cb + 4]);
      float vv[8] = {v0[0], v0[1], v0[2], v0[3], v1[0], v1[1], v1[2], v1[3]};
      union { ushort us[8]; int4 i4; } pk;
#pragma unroll
      for (int j = 0; j < 8; j++) pk.us[j] = f2bf(vv[j]);
      *reinterpret_cast<int4*>(
          out + (((size_t)b * H + h0 + h2 * 8 + fr) * W + w0 + p) * 64 + co8 * 8) = pk.i4;
    }
  }
}

// ---------------- edge stats + MLP + softmax + blend (one kernel) ----------------
__global__ __launch_bounds__(256) void mlp_k(
    const ushort* __restrict__ x1, const float* __restrict__ Ssum,
    const float* __restrict__ dww, const float* __restrict__ dwb,
    const float* __restrict__ c1w, const float* __restrict__ c1b,
    const float* __restrict__ c2w, const float* __restrict__ c2b,
    const float* __restrict__ basep, ushort* __restrict__ wmf) {
  int b = blockIdx.x;
  int t = threadIdx.x;
  __shared__ float red[256];
  __shared__ float eg[4][64], corn[4][64];
  __shared__ float pm[64], p1[64], p2[16];
  const size_t bb = (size_t)b * HWc * 64;
#pragma unroll
  for (int st = 0; st < 4; st++) {
    float s = 0.f;
    for (int i = 0; i < 64; i++) {
      int idx = i * 256 + t;
      int pix = idx >> 6, c = idx & 63;
      size_t off;
      if (st == 0)      off = ((size_t)pix) * 64 + c;
      else if (st == 1) off = ((size_t)(H - 1) * W + pix) * 64 + c;
      else if (st == 2) off = ((size_t)pix * W) * 64 + c;
      else              off = ((size_t)pix * W + (W - 1)) * 64 + c;
      s += bf2f(x1[bb + off]);
    }
    red[t] = s;
    __syncthreads();
    if (t < 64) eg[st][t] = red[t] + red[t + 64] + red[t + 128] + red[t + 192];
    __syncthreads();
  }
  if (t < 64) {
    corn[0][t] = bf2f(x1[bb + t]);
    corn[1][t] = bf2f(x1[bb + ((size_t)(W - 1)) * 64 + t]);
    corn[2][t] = bf2f(x1[bb + ((size_t)(H - 1) * W) * 64 + t]);
    corn[3][t] = bf2f(x1[bb + ((size_t)(H - 1) * W + W - 1) * 64 + t]);
  }
  __syncthreads();
  if (t < 64) {
    float S = Ssum[b * 64 + t];
    float R0 = eg[0][t], Rh = eg[1][t], C0 = eg[2][t], Cw = eg[3][t];
    float X00 = corn[0][t], X0w = corn[1][t], Xh0 = corn[2][t], Xhw = corn[3][t];
    float acc = 0.f;
#pragma unroll
    for (int ky = 0; ky < 3; ky++)
#pragma unroll
      for (int kx = 0; kx < 3; kx++) {
        float T = S;
        if (ky == 2) T -= R0;
        if (ky == 0) T -= Rh;
        if (kx == 2) T -= C0;
        if (kx == 0) T -= Cw;
        if (ky == 2 && kx == 2) T += X00;
        if (ky == 2 && kx == 0) T += X0w;
        if (ky == 0 && kx == 2) T += Xh0;
        if (ky == 0 && kx == 0) T += Xhw;
        acc += dww[t * 9 + ky * 3 + kx] * T;
      }
    pm[t] = acc * (1.f / HWc) + dwb[t];
  }
  __syncthreads();
  if (t < 64) {
    float a = c1b[t];
    for (int ci = 0; ci < 64; ci++) a += pm[ci] * c1w[t * 64 + ci];
    p1[t] = fmaxf(a, 0.f);
  }
  __syncthreads();
  if (t < N) {
    float a2 = c2b[t];
    for (int ci = 0; ci < 64; ci++) a2 += p1[ci] * c2w[t * 64 + ci];
    p2[t] = a2;
  }
  __syncthreads();
  float m = -1e30f;
  for (int n = 0; n < N; n++) m = fmaxf(m, p2[n]);
  float ev[N], s = 0.f;
  for (int n = 0; n < N; n++) { ev[n] = expf(p2[n] - m); s += ev[n]; }
  float inv = 1.f / s;
  for (int idx = t; idx < 4096; idx += 256) {
    int j = idx & 7, lane = (idx >> 3) & 63, cf = (idx >> 9) & 3, s2 = idx >> 11;
    int k = (s2 << 5) + ((lane >> 4) << 3) + j;
    int l = (cf << 4) + (lane & 15);
    float acc = 0.f;
    for (int n = 0; n < N; n++) acc += ev[n] * inv * basep[n * 4096 + k * 64 + l];
    wmf[(size_t)b * 4096 + idx] = f2bf(acc);
  }
}

__global__ void zero_k(float* p, int n) {
  int i = blockIdx.x * 256 + threadIdx.x;
  if (i < n) p[i] = 0.f;
}

extern "C" void kernel_launch(void* const* d_in, const int* in_sizes, int n_in,
                              void* d_out, int out_size, void* d_ws, size_t ws_size,
                              hipStream_t stream) {
  const float* x       = (const float*)d_in[0];
  const float* ln_g    = (const float*)d_in[1];
  const float* ln_b    = (const float*)d_in[2];
  const float* conv3_w = (const float*)d_in[3];
  const float* conv3_b = (const float*)d_in[4];
  const float* dw_w    = (const float*)d_in[5];
  const float* dw_b    = (const float*)d_in[6];
  const float* c1_w    = (const float*)d_in[7];
  const float* c1_b    = (const float*)d_in[8];
  const float* c2_w    = (const float*)d_in[9];
  const float* c2_b    = (const float*)d_in[10];
  const float* basep   = (const float*)d_in[11];
  const float* up_w    = (const float*)d_in[12];
  const float* up_b    = (const float*)d_in[13];
  const float* down_w  = (const float*)d_in[14];
  const float* down_b  = (const float*)d_in[15];
  float* out = (float*)d_out;

  char* wsb = (char*)d_ws;
  size_t big = (size_t)B * HWc * 64 * sizeof(ushort);  // 67,108,864
  ushort* bufA   = (ushort*)wsb;
  ushort* bufB   = (ushort*)(wsb + big);
  ushort* wfrags = (ushort*)(wsb + 2 * big);
  ushort* wmfrag = (ushort*)(wsb + 2 * big + 3 * 36864 * 2);
  float*  Ssum   = (float*)(wsb + 2 * big + 3 * 36864 * 2 + 8 * 4096 * 2);
  const ushort* zbuf = (const ushort*)(Ssum + 512);

  prep_w<<<54, 256, 0, stream>>>(conv3_w, up_w, down_w, wfrags);
  zero_k<<<8, 256, 0, stream>>>(Ssum, 2048);
  // 1. LN: x -> bufA (NHWC bf16)
  ln_k<<<dim3(HWc / 256, B), 256, 0, stream>>>(x, ln_g, ln_b, bufA);
  // 2. conv3 + GELU + tile-sum: bufA -> bufB (x1), Ssum
  conv_mfma<1, 0, 1><<<dim3(16, 16, B), 256, 0, stream>>>(
      bufA, wfrags + 0 * 36864, conv3_b, nullptr, bufB, nullptr, Ssum, zbuf);
  // 3. edge stats + MLP + blend: -> wmfrag
  mlp_k<<<B, 256, 0, stream>>>(bufB, Ssum, dw_w, dw_b, c1_w, c1_b, c2_w, c2_b,
                               basep, wmfrag);
  // 4. fused up conv + mix: bufB -> bufA (xm2, NHWC bf16)
  upmix_mfma<<<dim3(16, 16, B), 256, 0, stream>>>(
      bufB, wfrags + 1 * 36864, up_b, wmfrag, bufA, zbuf);
  // 5. down conv + residual: bufA -> out (NCHW fp32)
  conv_mfma<0, 1, 0><<<dim3(16, 16, B), 256, 0, stream>>>(
      bufA, wfrags + 2 * 36864, down_b, x, nullptr, out, Ssum, zbuf);
}

// Round 23
// 271.958 us; speedup vs baseline: 1.1308x; 1.1308x over previous
//
#include <hip/hip_runtime.h>
#include <math.h>

constexpr int B = 8, C = 64, H = 256, W = 256, HWc = H * W, N = 10;

typedef short bf8 __attribute__((ext_vector_type(8)));    // 8 x bf16 (4 VGPR)
typedef float f4  __attribute__((ext_vector_type(4)));    // MFMA accum
typedef unsigned short ushort;

__device__ __forceinline__ ushort f2bf(float f) {
  unsigned u = __builtin_bit_cast(unsigned, f);
  unsigned r = (u + 0x7fffu + ((u >> 16) & 1u)) >> 16;
  return (ushort)r;
}
__device__ __forceinline__ float bf2f(ushort h) {
  unsigned u = ((unsigned)h) << 16;
  return __builtin_bit_cast(float, u);
}

// ---------------- LayerNorm: NCHW fp32 -> NHWC bf16 ----------------
__global__ __launch_bounds__(256) void ln_k(
    const float* __restrict__ x, const float* __restrict__ g,
    const float* __restrict__ bt, ushort* __restrict__ xn) {
  int pix = blockIdx.x * 256 + threadIdx.x;
  int b = blockIdx.y;
  const float* xp = x + (size_t)b * C * HWc + pix;
  float v[64];
  float s = 0.f, s2 = 0.f;
#pragma unroll
  for (int c = 0; c < 64; c++) {
    v[c] = xp[(size_t)c * HWc];
    s += v[c]; s2 += v[c] * v[c];
  }
  float mu = s * (1.f / 64);
  float var = s2 * (1.f / 64) - mu * mu;
  float rstd = rsqrtf(var + 1e-5f);
  ushort* op = xn + ((size_t)b * HWc + pix) * 64;
#pragma unroll
  for (int ch = 0; ch < 8; ch++) {
    union { ushort us[8]; int4 v4; } pk;
#pragma unroll
    for (int j = 0; j < 8; j++) {
      int c = ch * 8 + j;
      pk.us[j] = f2bf((v[c] - mu) * rstd * g[c] + bt[c]);
    }
    *reinterpret_cast<int4*>(op + ch * 8) = pk.v4;
  }
}

// ---------------- weight prep: OIHW fp32 -> MFMA fragment layout bf16 ----------------
__global__ void prep_w(const float* __restrict__ w3, const float* __restrict__ wu,
                       const float* __restrict__ wd, ushort* __restrict__ frags) {
  int idx = blockIdx.x * 256 + threadIdx.x;
  if (idx >= 3 * 4608) return;
  int conv = idx / 4608, r = idx % 4608;
  int s = r >> 8, cf = (r >> 6) & 3, lane = r & 63;
  const float* w = (conv == 0) ? w3 : (conv == 1) ? wu : wd;
  int co = (cf << 4) + (lane & 15);
  int tap = s >> 1;
  ushort* o = frags + conv * 36864 + ((size_t)r) * 8;
#pragma unroll
  for (int j = 0; j < 8; j++) {
    int ci = ((s & 1) << 5) + ((lane >> 4) << 3) + j;
    o[j] = f2bf(w[(co * 64 + ci) * 9 + tap]);
  }
}

// bijective XCD swizzle (T1) for nwg = 16*16*8 = 2048: chunk = 2048/8 = 256.
// sw = (lin%8)*256 + lin/8 is a bijection [0,2048)->[0,2048).
// (R22 crash: <<9 assumed nwg=4096 -> b up to 14, OOB. ERRATA #11 class.)
__device__ __forceinline__ void xcd_tile(int& b, int& h0, int& w0) {
  int lin = (blockIdx.z << 8) + (blockIdx.y << 4) + blockIdx.x;
  int sw  = ((lin & 7) << 8) + (lin >> 3);
  b  = sw >> 8;
  h0 = ((sw >> 4) & 15) << 4;
  w0 = (sw & 15) << 4;
}

// ======== zero-register staging via global_load_lds (rule #21 layout) ========
typedef __attribute__((address_space(3))) unsigned lds_u32;
typedef __attribute__((address_space(1))) const unsigned glb_u32;

__device__ __forceinline__ void stage_gll(
    char* ldsbuf, const ushort* __restrict__ in, const ushort* __restrict__ zbuf,
    int b, int h0, int w0, int ch2, int tid) {
  int wave = tid >> 6, lane = tid & 63;
#pragma unroll
  for (int it = 0; it < 6; it++) {
    int idx = it * 256 + wave * 64 + lane;
    int pix = idx >> 2, ch = idx & 3;
    int r = pix / 18, c = pix % 18;
    int gh = h0 + r - 1, gw = w0 + c - 1;
    int chs = ch ^ ((c >> 1) & 3);                 // pre-swizzled source channel
    bool ok = (idx < 1296) && (gh >= 0) && (gh < H) && (gw >= 0) && (gw < W);
    const ushort* src = ok
        ? in + (((size_t)b * H + gh) * W + gw) * 64 + ch2 * 32 + chs * 8
        : zbuf;
    char* dst = ldsbuf + (it * 256 + wave * 64) * 16;
    __builtin_amdgcn_global_load_lds((glb_u32*)(const void*)src,
                                     (lds_u32*)(void*)dst, 16, 0, 0);
  }
}

// compute one ci-half (weights loaded per-dx; R19 showed preload is perf-null)
__device__ __forceinline__ void compute_half(
    const char* lds, const bf8* __restrict__ wf, int ch2,
    int wave, int lm, int lk, f4 (&acc)[16]) {
#pragma unroll
  for (int dx = 0; dx < 3; dx++) {
    bf8 wb3[3];
#pragma unroll
    for (int dy = 0; dy < 3; dy++) {
      int s = ((dy * 3 + dx) << 1) | ch2;
      wb3[dy] = wf[(s * 4 + wave) * 64 + (lk << 4) + lm];
    }
    int lc = lm + dx;
    int swz = ((lc >> 1) & 3) << 4;
#pragma unroll
    for (int hf = 0; hf < 2; hf++) {
      bf8 a[10];
#pragma unroll
      for (int r = 0; r < 10; r++) {
        int row = hf * 8 + r;
        int off = (((row * 18 + lc) << 6) + (lk << 4)) ^ swz;
        a[r] = *reinterpret_cast<const bf8*>(lds + off);
      }
#pragma unroll
      for (int dy = 0; dy < 3; dy++)
#pragma unroll
        for (int f = 0; f < 8; f++)
          acc[hf * 8 + f] =
              __builtin_amdgcn_mfma_f32_16x16x32_bf16(a[f + dy], wb3[dy], acc[hf * 8 + f], 0, 0, 0);
    }
  }
}

// counted-vmcnt gate + raw barrier
#define VM_GATE(NN)                                                       \
  asm volatile("s_waitcnt vmcnt(" #NN ")" ::: "memory");                  \
  __builtin_amdgcn_s_barrier();                                           \
  __builtin_amdgcn_sched_barrier(0);

// block-level per-channel reduce -> one atomic per channel (transposed, conflict-free)
__device__ __forceinline__ void red_at(
    float* ldsf, const float (&a)[8], float* __restrict__ Ssum,
    int b, int tid) {
  __syncthreads();
#pragma unroll
  for (int j = 0; j < 8; j++) ldsf[j * 256 + tid] = a[j];
  __syncthreads();
  if (tid < 64) {
    float s = 0.f;
#pragma unroll
    for (int kk = 0; kk < 32; kk++) s += ldsf[(tid & 7) * 256 + kk * 8 + (tid >> 3)];
    atomicAdd(&Ssum[b * 64 + tid], s);
  }
}

// ---------------- MFMA implicit-GEMM 3x3 conv ----------------
// OM=0: out NHWC bf16 (+GELU), 2-half LDS-transpose epilogue.
// OM=1: out NCHW fp32 + residual, 2-half LDS-transpose epilogue + resid prefetch.
template <int ACT, int OM, int DOST>
__global__ __launch_bounds__(256, 3) void conv_mfma(
    const ushort* __restrict__ in, const ushort* __restrict__ wfrag,
    const float* __restrict__ bias, const float* __restrict__ resid,
    ushort* __restrict__ outb, float* __restrict__ outf,
    float* __restrict__ Ssum, const ushort* __restrict__ zbuf) {
  __shared__ char lds[2 * 24576];  // padded halves; epilogue reuses 32 KB
  char* ldsA = lds;
  char* ldsB = lds + 24576;
  int tid = threadIdx.x;
  int b, h0, w0;
  xcd_tile(b, h0, w0);
  int wave = tid >> 6, lane = tid & 63;
  int lm = lane & 15, lk = lane >> 4;
  const bf8* wf = reinterpret_cast<const bf8*>(wfrag);

  f4 acc[16];
  {
    float bv = bias[(wave << 4) + lm];
    f4 ini = {bv, bv, bv, bv};
#pragma unroll
    for (int f = 0; f < 16; f++) acc[f] = ini;
  }

  stage_gll(ldsA, in, zbuf, b, h0, w0, 0, tid);
  stage_gll(ldsB, in, zbuf, b, h0, w0, 1, tid);
  VM_GATE(6)
  compute_half(ldsA, wf, 0, wave, lm, lk, acc);
  VM_GATE(0)
  compute_half(ldsB, wf, 1, wave, lm, lk, acc);

  float* ldsf = reinterpret_cast<float*>(lds);
  if (OM == 0) {
    float s8[8];
    if (DOST) {
#pragma unroll
      for (int j = 0; j < 8; j++) s8[j] = 0.f;
    }
    // 2 halves of 8 pixel-rows: 8*16 px * 64 co * 4B = 32 KB
    for (int h2 = 0; h2 < 2; h2++) {
      __syncthreads();
#pragma unroll
      for (int fr = 0; fr < 8; fr++) {
        int f = h2 * 8 + fr;
        int co = (wave << 4) + lm;
#pragma unroll
        for (int r = 0; r < 4; r++) {
          int p = (lk << 2) + r;
          ldsf[fr * 1024 + p * 64 + (co ^ ((p & 12) << 2))] = acc[f][r];
        }
      }
      __syncthreads();
#pragma unroll
      for (int i = 0; i < 4; i++) {
        int q2 = i * 256 + tid;               // 0..1023
        int co8 = q2 & 7, p = (q2 >> 3) & 15, fr = q2 >> 7;
        int cb = (co8 * 8) ^ ((p & 12) << 2);
        f4 v0 = *reinterpret_cast<f4*>(&ldsf[fr * 1024 + p * 64 + cb]);
        f4 v1 = *reinterpret_cast<f4*>(&ldsf[fr * 1024 + p * 64 + cb + 4]);
        float vv[8] = {v0[0], v0[1], v0[2], v0[3], v1[0], v1[1], v1[2], v1[3]};
        union { ushort us[8]; int4 i4; } pk;
#pragma unroll
        for (int j = 0; j < 8; j++) {
          float v = vv[j];
          if (ACT) v = 0.5f * v * (1.f + erff(v * 0.70710678118654752f));
          if (DOST) s8[j] += v;
          pk.us[j] = f2bf(v);
        }
        *reinterpret_cast<int4*>(
            outb + (((size_t)b * H + h0 + h2 * 8 + fr) * W + w0 + p) * 64 + co8 * 8) = pk.i4;
      }
    }
    if (DOST) red_at(ldsf, s8, Ssum, b, tid);
  } else {
    // NCHW fp32 + residual; 2 halves of 32 co each + phase-local resid prefetch
    for (int h2 = 0; h2 < 2; h2++) {
      __syncthreads();
      if ((wave >> 1) == h2) {
        int co32 = ((wave & 1) << 4) + lm;
#pragma unroll
        for (int f = 0; f < 16; f++) {
          int pxl = (f << 4) + (lk << 2);
          int pxs = pxl ^ ((lm & 7) << 2);
          *reinterpret_cast<f4*>(&ldsf[co32 * 256 + pxs]) = acc[f];
        }
      }
      float4 rv[8];
#pragma unroll
      for (int i = 0; i < 8; i++) {
        int q2 = i * 256 + tid;               // 0..2047
        int chunk = q2 & 63, co32 = q2 >> 6;
        int pq = chunk * 4;
        int co = h2 * 32 + co32;
        size_t o = ((size_t)(b * 64 + co)) * HWc +
                   (size_t)(h0 + (pq >> 4)) * W + w0 + (pq & 15);
        rv[i] = *reinterpret_cast<const float4*>(resid + o);
      }
      __syncthreads();
#pragma unroll
      for (int i = 0; i < 8; i++) {
        int q2 = i * 256 + tid;
        int chunk = q2 & 63, co32 = q2 >> 6;
        int pq = chunk * 4;                          // UNSWIZZLED pixel base
        int pxs = pq ^ ((co32 & 7) << 2);            // swizzled LDS addr
        f4 v = *reinterpret_cast<f4*>(&ldsf[co32 * 256 + pxs]);
        int co = h2 * 32 + co32;
        size_t o = ((size_t)(b * 64 + co)) * HWc +
                   (size_t)(h0 + (pq >> 4)) * W + w0 + (pq & 15);
        float4 ov;
        ov.x = v[0] + rv[i].x; ov.y = v[1] + rv[i].y;
        ov.z = v[2] + rv[i].z; ov.w = v[3] + rv[i].w;
        *reinterpret_cast<float4*>(outf + o) = ov;
      }
    }
  }
}

// ---------------- fused up-conv + channel mix ----------------
__global__ __launch_bounds__(256, 2) void upmix_mfma(
    const ushort* __restrict__ in, const ushort* __restrict__ wfrag,
    const float* __restrict__ bias, const ushort* __restrict__ wmf,
    ushort* __restrict__ out, const ushort* __restrict__ zbuf) {
  __shared__ char ldsS[24576];   // stage half 0 (padded)
  __shared__ char ldsX[32768];   // stage half 1 / xm tile / epilogue
  int tid = threadIdx.x;
  int b, h0, w0;
  xcd_tile(b, h0, w0);
  int wave = tid >> 6, lane = tid & 63;
  int lm = lane & 15, lk = lane >> 4;
  const bf8* wf = reinterpret_cast<const bf8*>(wfrag);

  const bf8* wmb = reinterpret_cast<const bf8*>(wmf + (size_t)b * 4096);
  bf8 wm[2];
#pragma unroll
  for (int s = 0; s < 2; s++) wm[s] = wmb[(s * 4 + wave) * 64 + lane];

  f4 acc[16];
  {
    float bv = bias[(wave << 4) + lm];
    f4 ini = {bv, bv, bv, bv};
#pragma unroll
    for (int f = 0; f < 16; f++) acc[f] = ini;
  }

  stage_gll(ldsS, in, zbuf, b, h0, w0, 0, tid);
  stage_gll(ldsX, in, zbuf, b, h0, w0, 1, tid);
  VM_GATE(6)
  compute_half(ldsS, wf, 0, wave, lm, lk, acc);
  VM_GATE(0)
  compute_half(ldsX, wf, 1, wave, lm, lk, acc);
  __syncthreads();   // all waves done reading ldsX before scatter overwrites it

  // scatter acc -> xm tile (bf16) in mix staging layout
#pragma unroll
  for (int f = 0; f < 16; f++) {
#pragma unroll
    for (int r = 0; r < 4; r++) {
      int pc = (lk << 2) + r;
      int pix = (f << 4) + pc;
      int off = ((pix << 7) + ((wave << 4) + lm) * 2) ^ ((pc & 7) << 4);
      *reinterpret_cast<ushort*>(ldsX + off) = f2bf(acc[f][r]);
    }
  }
  __syncthreads();

  f4 acc2[16];
#pragma unroll
  for (int f = 0; f < 16; f++) acc2[f] = (f4){0.f, 0.f, 0.f, 0.f};
#pragma unroll
  for (int s = 0; s < 2; s++) {
    int kbyte = ((s << 5) + (lk << 3)) << 1;
#pragma unroll
    for (int f = 0; f < 16; f++) {
      int off = ((((f << 4) + lm) << 7) + kbyte) ^ ((lm & 7) << 4);
      bf8 a = *reinterpret_cast<const bf8*>(ldsX + off);
      acc2[f] = __builtin_amdgcn_mfma_f32_16x16x32_bf16(a, wm[s], acc2[f], 0, 0, 0);
    }
  }

  // epilogue: 2-half transpose via ldsX (32 KB) -> NHWC bf16
  float* ldsf = reinterpret_cast<float*>(ldsX);
  for (int h2 = 0; h2 < 2; h2++) {
    __syncthreads();
#pragma unroll
    for (int fr = 0; fr < 8; fr++) {
      int f = h2 * 8 + fr;
      int co = (wave << 4) + lm;
#pragma unroll
      for (int r = 0; r < 4; r++) {
        int p = (lk << 2) + r;
        ldsf[fr * 1024 + p * 64 + (co ^ ((p & 12) << 2))] = acc2[f][r];
      }
    }
    __syncthreads();
#pragma unroll
    for (int i = 0; i < 4; i++) {
      int q2 = i * 256 + tid;
      int co8 = q2 & 7, p = (q2 >> 3) & 15, fr = q2 >> 7;
      int cb = (co8 * 8) ^ ((p & 12) << 2);
      f4 v0 = *reinterpret_cast<f4*>(&ldsf[fr * 1024 + p * 64 + cb]);
      f4 v1 = *reinterpret_cast<f4*>(&ldsf[fr * 1024 + p * 64 + cb + 4]);
      float vv[8] = {v0[0], v0[1], v0[2], v0[3], v1[0], v1[1], v1[2], v1[3]};
      union { ushort us[8]; int4 i4; } pk;
#pragma unroll
      for (int j = 0; j < 8; j++) pk.us[j] = f2bf(vv[j]);
      *reinterpret_cast<int4*>(
          out + (((size_t)b * H + h0 + h2 * 8 + fr) * W + w0 + p) * 64 + co8 * 8) = pk.i4;
    }
  }
}

// ---------------- edge stats + MLP + softmax + blend (one kernel) ----------------
__global__ __launch_bounds__(256) void mlp_k(
    const ushort* __restrict__ x1, const float* __restrict__ Ssum,
    const float* __restrict__ dww, const float* __restrict__ dwb,
    const float* __restrict__ c1w, const float* __restrict__ c1b,
    const float* __restrict__ c2w, const float* __restrict__ c2b,
    const float* __restrict__ basep, ushort* __restrict__ wmf) {
  int b = blockIdx.x;
  int t = threadIdx.x;
  __shared__ float red[256];
  __shared__ float eg[4][64], corn[4][64];
  __shared__ float pm[64], p1[64], p2[16];
  const size_t bb = (size_t)b * HWc * 64;
#pragma unroll
  for (int st = 0; st < 4; st++) {
    float s = 0.f;
    for (int i = 0; i < 64; i++) {
      int idx = i * 256 + t;
      int pix = idx >> 6, c = idx & 63;
      size_t off;
      if (st == 0)      off = ((size_t)pix) * 64 + c;
      else if (st == 1) off = ((size_t)(H - 1) * W + pix) * 64 + c;
      else if (st == 2) off = ((size_t)pix * W) * 64 + c;
      else              off = ((size_t)pix * W + (W - 1)) * 64 + c;
      s += bf2f(x1[bb + off]);
    }
    red[t] = s;
    __syncthreads();
    if (t < 64) eg[st][t] = red[t] + red[t + 64] + red[t + 128] + red[t + 192];
    __syncthreads();
  }
  if (t < 64) {
    corn[0][t] = bf2f(x1[bb + t]);
    corn[1][t] = bf2f(x1[bb + ((size_t)(W - 1)) * 64 + t]);
    corn[2][t] = bf2f(x1[bb + ((size_t)(H - 1) * W) * 64 + t]);
    corn[3][t] = bf2f(x1[bb + ((size_t)(H - 1) * W + W - 1) * 64 + t]);
  }
  __syncthreads();
  if (t < 64) {
    float S = Ssum[b * 64 + t];
    float R0 = eg[0][t], Rh = eg[1][t], C0 = eg[2][t], Cw = eg[3][t];
    float X00 = corn[0][t], X0w = corn[1][t], Xh0 = corn[2][t], Xhw = corn[3][t];
    float acc = 0.f;
#pragma unroll
    for (int ky = 0; ky < 3; ky++)
#pragma unroll
      for (int kx = 0; kx < 3; kx++) {
        float T = S;
        if (ky == 2) T -= R0;
        if (ky == 0) T -= Rh;
        if (kx == 2) T -= C0;
        if (kx == 0) T -= Cw;
        if (ky == 2 && kx == 2) T += X00;
        if (ky == 2 && kx == 0) T += X0w;
        if (ky == 0 && kx == 2) T += Xh0;
        if (ky == 0 && kx == 0) T += Xhw;
        acc += dww[t * 9 + ky * 3 + kx] * T;
      }
    pm[t] = acc * (1.f / HWc) + dwb[t];
  }
  __syncthreads();
  if (t < 64) {
    float a = c1b[t];
    for (int ci = 0; ci < 64; ci++) a += pm[ci] * c1w[t * 64 + ci];
    p1[t] = fmaxf(a, 0.f);
  }
  __syncthreads();
  if (t < N) {
    float a2 = c2b[t];
    for (int ci = 0; ci < 64; ci++) a2 += p1[ci] * c2w[t * 64 + ci];
    p2[t] = a2;
  }
  __syncthreads();
  float m = -1e30f;
  for (int n = 0; n < N; n++) m = fmaxf(m, p2[n]);
  float ev[N], s = 0.f;
  for (int n = 0; n < N; n++) { ev[n] = expf(p2[n] - m); s += ev[n]; }
  float inv = 1.f / s;
  for (int idx = t; idx < 4096; idx += 256) {
    int j = idx & 7, lane = (idx >> 3) & 63, cf = (idx >> 9) & 3, s2 = idx >> 11;
    int k = (s2 << 5) + ((lane >> 4) << 3) + j;
    int l = (cf << 4) + (lane & 15);
    float acc = 0.f;
    for (int n = 0; n < N; n++) acc += ev[n] * inv * basep[n * 4096 + k * 64 + l];
    wmf[(size_t)b * 4096 + idx] = f2bf(acc);
  }
}

__global__ void zero_k(float* p, int n) {
  int i = blockIdx.x * 256 + threadIdx.x;
  if (i < n) p[i] = 0.f;
}

extern "C" void kernel_launch(void* const* d_in, const int* in_sizes, int n_in,
                              void* d_out, int out_size, void* d_ws, size_t ws_size,
                              hipStream_t stream) {
  const float* x       = (const float*)d_in[0];
  const float* ln_g    = (const float*)d_in[1];
  const float* ln_b    = (const float*)d_in[2];
  const float* conv3_w = (const float*)d_in[3];
  const float* conv3_b = (const float*)d_in[4];
  const float* dw_w    = (const float*)d_in[5];
  const float* dw_b    = (const float*)d_in[6];
  const float* c1_w    = (const float*)d_in[7];
  const float* c1_b    = (const float*)d_in[8];
  const float* c2_w    = (const float*)d_in[9];
  const float* c2_b    = (const float*)d_in[10];
  const float* basep   = (const float*)d_in[11];
  const float* up_w    = (const float*)d_in[12];
  const float* up_b    = (const float*)d_in[13];
  const float* down_w  = (const float*)d_in[14];
  const float* down_b  = (const float*)d_in[15];
  float* out = (float*)d_out;

  char* wsb = (char*)d_ws;
  size_t big = (size_t)B * HWc * 64 * sizeof(ushort);  // 67,108,864
  ushort* bufA   = (ushort*)wsb;
  ushort* bufB   = (ushort*)(wsb + big);
  ushort* wfrags = (ushort*)(wsb + 2 * big);
  ushort* wmfrag = (ushort*)(wsb + 2 * big + 3 * 36864 * 2);
  float*  Ssum   = (float*)(wsb + 2 * big + 3 * 36864 * 2 + 8 * 4096 * 2);
  const ushort* zbuf = (const ushort*)(Ssum + 512);

  prep_w<<<54, 256, 0, stream>>>(conv3_w, up_w, down_w, wfrags);
  zero_k<<<8, 256, 0, stream>>>(Ssum, 2048);
  // 1. LN: x -> bufA (NHWC bf16)
  ln_k<<<dim3(HWc / 256, B), 256, 0, stream>>>(x, ln_g, ln_b, bufA);
  // 2. conv3 + GELU + tile-sum: bufA -> bufB (x1), Ssum
  conv_mfma<1, 0, 1><<<dim3(16, 16, B), 256, 0, stream>>>(
      bufA, wfrags + 0 * 36864, conv3_b, nullptr, bufB, nullptr, Ssum, zbuf);
  // 3. edge stats + MLP + blend: -> wmfrag
  mlp_k<<<B, 256, 0, stream>>>(bufB, Ssum, dw_w, dw_b, c1_w, c1_b, c2_w, c2_b,
                               basep, wmfrag);
  // 4. fused up conv + mix: bufB -> bufA (xm2, NHWC bf16)
  upmix_mfma<<<dim3(16, 16, B), 256, 0, stream>>>(
      bufB, wfrags + 1 * 36864, up_b, wmfrag, bufA, zbuf);
  // 5. down conv + residual: bufA -> out (NCHW fp32)
  conv_mfma<0, 1, 0><<<dim3(16, 16, B), 256, 0, stream>>>(
      bufA, wfrags + 2 * 36864, down_b, x, nullptr, out, Ssum, zbuf);
}

// Round 24
// 265.769 us; speedup vs baseline: 1.1571x; 1.0233x over previous
//
#include <hip/hip_runtime.h>
#include <math.h>

constexpr int B = 8, C = 64, H = 256, W = 256, HWc = H * W, N = 10;

typedef short bf8 __attribute__((ext_vector_type(8)));    // 8 x bf16 (4 VGPR)
typedef float f4  __attribute__((ext_vector_type(4)));    // MFMA accum
typedef unsigned short ushort;

__device__ __forceinline__ ushort f2bf(float f) {
  unsigned u = __builtin_bit_cast(unsigned, f);
  unsigned r = (u + 0x7fffu + ((u >> 16) & 1u)) >> 16;
  return (ushort)r;
}
__device__ __forceinline__ float bf2f(ushort h) {
  unsigned u = ((unsigned)h) << 16;
  return __builtin_bit_cast(float, u);
}

// ---------------- LayerNorm: NCHW fp32 -> NHWC bf16 ----------------
__global__ __launch_bounds__(256) void ln_k(
    const float* __restrict__ x, const float* __restrict__ g,
    const float* __restrict__ bt, ushort* __restrict__ xn) {
  int pix = blockIdx.x * 256 + threadIdx.x;
  int b = blockIdx.y;
  const float* xp = x + (size_t)b * C * HWc + pix;
  float v[64];
  float s = 0.f, s2 = 0.f;
#pragma unroll
  for (int c = 0; c < 64; c++) {
    v[c] = xp[(size_t)c * HWc];
    s += v[c]; s2 += v[c] * v[c];
  }
  float mu = s * (1.f / 64);
  float var = s2 * (1.f / 64) - mu * mu;
  float rstd = rsqrtf(var + 1e-5f);
  ushort* op = xn + ((size_t)b * HWc + pix) * 64;
#pragma unroll
  for (int ch = 0; ch < 8; ch++) {
    union { ushort us[8]; int4 v4; } pk;
#pragma unroll
    for (int j = 0; j < 8; j++) {
      int c = ch * 8 + j;
      pk.us[j] = f2bf((v[c] - mu) * rstd * g[c] + bt[c]);
    }
    *reinterpret_cast<int4*>(op + ch * 8) = pk.v4;
  }
}

// ---------------- weight prep: OIHW fp32 -> MFMA fragment layout bf16 ----------------
__global__ void prep_w(const float* __restrict__ w3, const float* __restrict__ wu,
                       const float* __restrict__ wd, ushort* __restrict__ frags) {
  int idx = blockIdx.x * 256 + threadIdx.x;
  if (idx >= 3 * 4608) return;
  int conv = idx / 4608, r = idx % 4608;
  int s = r >> 8, cf = (r >> 6) & 3, lane = r & 63;
  const float* w = (conv == 0) ? w3 : (conv == 1) ? wu : wd;
  int co = (cf << 4) + (lane & 15);
  int tap = s >> 1;
  ushort* o = frags + conv * 36864 + ((size_t)r) * 8;
#pragma unroll
  for (int j = 0; j < 8; j++) {
    int ci = ((s & 1) << 5) + ((lane >> 4) << 3) + j;
    o[j] = f2bf(w[(co * 64 + ci) * 9 + tap]);
  }
}

// bijective XCD swizzle (T1) for nwg = 2048: chunk = 256. Proven R23 (+10%).
__device__ __forceinline__ void xcd_tile(int& b, int& h0, int& w0) {
  int lin = (blockIdx.z << 8) + (blockIdx.y << 4) + blockIdx.x;
  int sw  = ((lin & 7) << 8) + (lin >> 3);
  b  = sw >> 8;
  h0 = ((sw >> 4) & 15) << 4;
  w0 = (sw & 15) << 4;
}

// ======== zero-register staging via global_load_lds, SECTOR-PAIRED ========
// R24: issue both ci-halves of each pixel-chunk back-to-back (A_it, B_it) so
// the two 64-B halves of every 128-B NHWC line are adjacent in the request
// stream -> full-line bursts (single-half streams had 50% sector utilization;
// convs measured 3.0 TB/s vs fill's 6.6).
typedef __attribute__((address_space(3))) unsigned lds_u32;
typedef __attribute__((address_space(1))) const unsigned glb_u32;

__device__ __forceinline__ void stage_pair(
    char* ldsA, char* ldsB, const ushort* __restrict__ in,
    const ushort* __restrict__ zbuf, int b, int h0, int w0, int tid) {
  int wave = tid >> 6, lane = tid & 63;
#pragma unroll
  for (int it = 0; it < 6; it++) {
    int idx = it * 256 + wave * 64 + lane;
    int pix = idx >> 2, ch = idx & 3;
    int r = pix / 18, c = pix % 18;
    int gh = h0 + r - 1, gw = w0 + c - 1;
    int chs = ch ^ ((c >> 1) & 3);                 // pre-swizzled source chunk
    bool ok = (idx < 1296) && (gh >= 0) && (gh < H) && (gw >= 0) && (gw < W);
    const ushort* base = in + (((size_t)b * H + gh) * W + gw) * 64 + chs * 8;
    const ushort* srcA = ok ? base : zbuf;
    const ushort* srcB = ok ? base + 32 : zbuf;
    char* dstA = ldsA + (it * 256 + wave * 64) * 16;
    char* dstB = ldsB + (it * 256 + wave * 64) * 16;
    __builtin_amdgcn_global_load_lds((glb_u32*)(const void*)srcA,
                                     (lds_u32*)(void*)dstA, 16, 0, 0);
    __builtin_amdgcn_global_load_lds((glb_u32*)(const void*)srcB,
                                     (lds_u32*)(void*)dstB, 16, 0, 0);
  }
}

// compute one ci-half (weights loaded per-dx; R19 showed preload is perf-null)
__device__ __forceinline__ void compute_half(
    const char* lds, const bf8* __restrict__ wf, int ch2,
    int wave, int lm, int lk, f4 (&acc)[16]) {
#pragma unroll
  for (int dx = 0; dx < 3; dx++) {
    bf8 wb3[3];
#pragma unroll
    for (int dy = 0; dy < 3; dy++) {
      int s = ((dy * 3 + dx) << 1) | ch2;
      wb3[dy] = wf[(s * 4 + wave) * 64 + (lk << 4) + lm];
    }
    int lc = lm + dx;
    int swz = ((lc >> 1) & 3) << 4;
#pragma unroll
    for (int hf = 0; hf < 2; hf++) {
      bf8 a[10];
#pragma unroll
      for (int r = 0; r < 10; r++) {
        int row = hf * 8 + r;
        int off = (((row * 18 + lc) << 6) + (lk << 4)) ^ swz;
        a[r] = *reinterpret_cast<const bf8*>(lds + off);
      }
#pragma unroll
      for (int dy = 0; dy < 3; dy++)
#pragma unroll
        for (int f = 0; f < 8; f++)
          acc[hf * 8 + f] =
              __builtin_amdgcn_mfma_f32_16x16x32_bf16(a[f + dy], wb3[dy], acc[hf * 8 + f], 0, 0, 0);
    }
  }
}

// counted-vmcnt gate + raw barrier
#define VM_GATE(NN)                                                       \
  asm volatile("s_waitcnt vmcnt(" #NN ")" ::: "memory");                  \
  __builtin_amdgcn_s_barrier();                                           \
  __builtin_amdgcn_sched_barrier(0);

// block-level per-channel reduce -> one atomic per channel (transposed, conflict-free)
__device__ __forceinline__ void red_at(
    float* ldsf, const float (&a)[8], float* __restrict__ Ssum,
    int b, int tid) {
  __syncthreads();
#pragma unroll
  for (int j = 0; j < 8; j++) ldsf[j * 256 + tid] = a[j];
  __syncthreads();
  if (tid < 64) {
    float s = 0.f;
#pragma unroll
    for (int kk = 0; kk < 32; kk++) s += ldsf[(tid & 7) * 256 + kk * 8 + (tid >> 3)];
    atomicAdd(&Ssum[b * 64 + tid], s);
  }
}

// ---------------- MFMA implicit-GEMM 3x3 conv ----------------
// OM=0: out NHWC bf16 (+GELU), 2-half LDS-transpose epilogue.
// OM=1: out NCHW fp32 + residual, 2-half LDS-transpose epilogue + resid prefetch.
template <int ACT, int OM, int DOST>
__global__ __launch_bounds__(256, 3) void conv_mfma(
    const ushort* __restrict__ in, const ushort* __restrict__ wfrag,
    const float* __restrict__ bias, const float* __restrict__ resid,
    ushort* __restrict__ outb, float* __restrict__ outf,
    float* __restrict__ Ssum, const ushort* __restrict__ zbuf) {
  __shared__ char lds[2 * 24576];  // padded halves; epilogue reuses 32 KB
  char* ldsA = lds;
  char* ldsB = lds + 24576;
  int tid = threadIdx.x;
  int b, h0, w0;
  xcd_tile(b, h0, w0);
  int wave = tid >> 6, lane = tid & 63;
  int lm = lane & 15, lk = lane >> 4;
  const bf8* wf = reinterpret_cast<const bf8*>(wfrag);

  f4 acc[16];
  {
    float bv = bias[(wave << 4) + lm];
    f4 ini = {bv, bv, bv, bv};
#pragma unroll
    for (int f = 0; f < 16; f++) acc[f] = ini;
  }

  stage_pair(ldsA, ldsB, in, zbuf, b, h0, w0, tid);
  VM_GATE(1)                     // A fully resident (A5 is 11th of 12 in order)
  compute_half(ldsA, wf, 0, wave, lm, lk, acc);
  VM_GATE(0)                     // B resident
  compute_half(ldsB, wf, 1, wave, lm, lk, acc);

  float* ldsf = reinterpret_cast<float*>(lds);
  if (OM == 0) {
    float s8[8];
    if (DOST) {
#pragma unroll
      for (int j = 0; j < 8; j++) s8[j] = 0.f;
    }
    // 2 halves of 8 pixel-rows: 8*16 px * 64 co * 4B = 32 KB
    for (int h2 = 0; h2 < 2; h2++) {
      __syncthreads();
#pragma unroll
      for (int fr = 0; fr < 8; fr++) {
        int f = h2 * 8 + fr;
        int co = (wave << 4) + lm;
#pragma unroll
        for (int r = 0; r < 4; r++) {
          int p = (lk << 2) + r;
          ldsf[fr * 1024 + p * 64 + (co ^ ((p & 12) << 2))] = acc[f][r];
        }
      }
      __syncthreads();
#pragma unroll
      for (int i = 0; i < 4; i++) {
        int q2 = i * 256 + tid;               // 0..1023
        int co8 = q2 & 7, p = (q2 >> 3) & 15, fr = q2 >> 7;
        int cb = (co8 * 8) ^ ((p & 12) << 2);
        f4 v0 = *reinterpret_cast<f4*>(&ldsf[fr * 1024 + p * 64 + cb]);
        f4 v1 = *reinterpret_cast<f4*>(&ldsf[fr * 1024 + p * 64 + cb + 4]);
        float vv[8] = {v0[0], v0[1], v0[2], v0[3], v1[0], v1[1], v1[2], v1[3]};
        union { ushort us[8]; int4 i4; } pk;
#pragma unroll
        for (int j = 0; j < 8; j++) {
          float v = vv[j];
          if (ACT) v = 0.5f * v * (1.f + erff(v * 0.70710678118654752f));
          if (DOST) s8[j] += v;
          pk.us[j] = f2bf(v);
        }
        *reinterpret_cast<int4*>(
            outb + (((size_t)b * H + h0 + h2 * 8 + fr) * W + w0 + p) * 64 + co8 * 8) = pk.i4;
      }
    }
    if (DOST) red_at(ldsf, s8, Ssum, b, tid);
  } else {
    // NCHW fp32 + residual; 2 halves of 32 co each + phase-local resid prefetch
    for (int h2 = 0; h2 < 2; h2++) {
      __syncthreads();
      if ((wave >> 1) == h2) {
        int co32 = ((wave & 1) << 4) + lm;
#pragma unroll
        for (int f = 0; f < 16; f++) {
          int pxl = (f << 4) + (lk << 2);
          int pxs = pxl ^ ((lm & 7) << 2);
          *reinterpret_cast<f4*>(&ldsf[co32 * 256 + pxs]) = acc[f];
        }
      }
      float4 rv[8];
#pragma unroll
      for (int i = 0; i < 8; i++) {
        int q2 = i * 256 + tid;               // 0..2047
        int chunk = q2 & 63, co32 = q2 >> 6;
        int pq = chunk * 4;
        int co = h2 * 32 + co32;
        size_t o = ((size_t)(b * 64 + co)) * HWc +
                   (size_t)(h0 + (pq >> 4)) * W + w0 + (pq & 15);
        rv[i] = *reinterpret_cast<const float4*>(resid + o);
      }
      __syncthreads();
#pragma unroll
      for (int i = 0; i < 8; i++) {
        int q2 = i * 256 + tid;
        int chunk = q2 & 63, co32 = q2 >> 6;
        int pq = chunk * 4;                          // UNSWIZZLED pixel base
        int pxs = pq ^ ((co32 & 7) << 2);            // swizzled LDS addr
        f4 v = *reinterpret_cast<f4*>(&ldsf[co32 * 256 + pxs]);
        int co = h2 * 32 + co32;
        size_t o = ((size_t)(b * 64 + co)) * HWc +
                   (size_t)(h0 + (pq >> 4)) * W + w0 + (pq & 15);
        float4 ov;
        ov.x = v[0] + rv[i].x; ov.y = v[1] + rv[i].y;
        ov.z = v[2] + rv[i].z; ov.w = v[3] + rv[i].w;
        *reinterpret_cast<float4*>(outf + o) = ov;
      }
    }
  }
}

// ---------------- fused up-conv + channel mix ----------------
__global__ __launch_bounds__(256, 2) void upmix_mfma(
    const ushort* __restrict__ in, const ushort* __restrict__ wfrag,
    const float* __restrict__ bias, const ushort* __restrict__ wmf,
    ushort* __restrict__ out, const ushort* __restrict__ zbuf) {
  __shared__ char ldsS[24576];   // stage half 0 (padded)
  __shared__ char ldsX[32768];   // stage half 1 / xm tile / epilogue
  int tid = threadIdx.x;
  int b, h0, w0;
  xcd_tile(b, h0, w0);
  int wave = tid >> 6, lane = tid & 63;
  int lm = lane & 15, lk = lane >> 4;
  const bf8* wf = reinterpret_cast<const bf8*>(wfrag);

  const bf8* wmb = reinterpret_cast<const bf8*>(wmf + (size_t)b * 4096);
  bf8 wm[2];
#pragma unroll
  for (int s = 0; s < 2; s++) wm[s] = wmb[(s * 4 + wave) * 64 + lane];

  f4 acc[16];
  {
    float bv = bias[(wave << 4) + lm];
    f4 ini = {bv, bv, bv, bv};
#pragma unroll
    for (int f = 0; f < 16; f++) acc[f] = ini;
  }

  stage_pair(ldsS, ldsX, in, zbuf, b, h0, w0, tid);
  VM_GATE(1)
  compute_half(ldsS, wf, 0, wave, lm, lk, acc);
  VM_GATE(0)
  compute_half(ldsX, wf, 1, wave, lm, lk, acc);
  __syncthreads();   // all waves done reading ldsX before scatter overwrites it

  // scatter acc -> xm tile (bf16) in mix staging layout
#pragma unroll
  for (int f = 0; f < 16; f++) {
#pragma unroll
    for (int r = 0; r < 4; r++) {
      int pc = (lk << 2) + r;
      int pix = (f << 4) + pc;
      int off = ((pix << 7) + ((wave << 4) + lm) * 2) ^ ((pc & 7) << 4);
      *reinterpret_cast<ushort*>(ldsX + off) = f2bf(acc[f][r]);
    }
  }
  __syncthreads();

  f4 acc2[16];
#pragma unroll
  for (int f = 0; f < 16; f++) acc2[f] = (f4){0.f, 0.f, 0.f, 0.f};
#pragma unroll
  for (int s = 0; s < 2; s++) {
    int kbyte = ((s << 5) + (lk << 3)) << 1;
#pragma unroll
    for (int f = 0; f < 16; f++) {
      int off = ((((f << 4) + lm) << 7) + kbyte) ^ ((lm & 7) << 4);
      bf8 a = *reinterpret_cast<const bf8*>(ldsX + off);
      acc2[f] = __builtin_amdgcn_mfma_f32_16x16x32_bf16(a, wm[s], acc2[f], 0, 0, 0);
    }
  }

  // epilogue: 2-half transpose via ldsX (32 KB) -> NHWC bf16
  float* ldsf = reinterpret_cast<float*>(ldsX);
  for (int h2 = 0; h2 < 2; h2++) {
    __syncthreads();
#pragma unroll
    for (int fr = 0; fr < 8; fr++) {
      int f = h2 * 8 + fr;
      int co = (wave << 4) + lm;
#pragma unroll
      for (int r = 0; r < 4; r++) {
        int p = (lk << 2) + r;
        ldsf[fr * 1024 + p * 64 + (co ^ ((p & 12) << 2))] = acc2[f][r];
      }
    }
    __syncthreads();
#pragma unroll
    for (int i = 0; i < 4; i++) {
      int q2 = i * 256 + tid;
      int co8 = q2 & 7, p = (q2 >> 3) & 15, fr = q2 >> 7;
      int cb = (co8 * 8) ^ ((p & 12) << 2);
      f4 v0 = *reinterpret_cast<f4*>(&ldsf[fr * 1024 + p * 64 + cb]);
      f4 v1 = *reinterpret_cast<f4*>(&ldsf[fr * 1024 + p * 64 + cb + 4]);
      float vv[8] = {v0[0], v0[1], v0[2], v0[3], v1[0], v1[1], v1[2], v1[3]};
      union { ushort us[8]; int4 i4; } pk;
#pragma unroll
      for (int j = 0; j < 8; j++) pk.us[j] = f2bf(vv[j]);
      *reinterpret_cast<int4*>(
          out + (((size_t)b * H + h0 + h2 * 8 + fr) * W + w0 + p) * 64 + co8 * 8) = pk.i4;
    }
  }
}

// ---------------- edge stats + MLP + softmax + blend (one kernel) ----------------
__global__ __launch_bounds__(256) void mlp_k(
    const ushort* __restrict__ x1, const float* __restrict__ Ssum,
    const float* __restrict__ dww, const float* __restrict__ dwb,
    const float* __restrict__ c1w, const float* __restrict__ c1b,
    const float* __restrict__ c2w, const float* __restrict__ c2b,
    const float* __restrict__ basep, ushort* __restrict__ wmf) {
  int b = blockIdx.x;
  int t = threadIdx.x;
  __shared__ float red[256];
  __shared__ float eg[4][64], corn[4][64];
  __shared__ float pm[64], p1[64], p2[16];
  const size_t bb = (size_t)b * HWc * 64;
#pragma unroll
  for (int st = 0; st < 4; st++) {
    float s = 0.f;
    for (int i = 0; i < 64; i++) {
      int idx = i * 256 + t;
      int pix = idx >> 6, c = idx & 63;
      size_t off;
      if (st == 0)      off = ((size_t)pix) * 64 + c;
      else if (st == 1) off = ((size_t)(H - 1) * W + pix) * 64 + c;
      else if (st == 2) off = ((size_t)pix * W) * 64 + c;
      else              off = ((size_t)pix * W + (W - 1)) * 64 + c;
      s += bf2f(x1[bb + off]);
    }
    red[t] = s;
    __syncthreads();
    if (t < 64) eg[st][t] = red[t] + red[t + 64] + red[t + 128] + red[t + 192];
    __syncthreads();
  }
  if (t < 64) {
    corn[0][t] = bf2f(x1[bb + t]);
    corn[1][t] = bf2f(x1[bb + ((size_t)(W - 1)) * 64 + t]);
    corn[2][t] = bf2f(x1[bb + ((size_t)(H - 1) * W) * 64 + t]);
    corn[3][t] = bf2f(x1[bb + ((size_t)(H - 1) * W + W - 1) * 64 + t]);
  }
  __syncthreads();
  if (t < 64) {
    float S = Ssum[b * 64 + t];
    float R0 = eg[0][t], Rh = eg[1][t], C0 = eg[2][t], Cw = eg[3][t];
    float X00 = corn[0][t], X0w = corn[1][t], Xh0 = corn[2][t], Xhw = corn[3][t];
    float acc = 0.f;
#pragma unroll
    for (int ky = 0; ky < 3; ky++)
#pragma unroll
      for (int kx = 0; kx < 3; kx++) {
        float T = S;
        if (ky == 2) T -= R0;
        if (ky == 0) T -= Rh;
        if (kx == 2) T -= C0;
        if (kx == 0) T -= Cw;
        if (ky == 2 && kx == 2) T += X00;
        if (ky == 2 && kx == 0) T += X0w;
        if (ky == 0 && kx == 2) T += Xh0;
        if (ky == 0 && kx == 0) T += Xhw;
        acc += dww[t * 9 + ky * 3 + kx] * T;
      }
    pm[t] = acc * (1.f / HWc) + dwb[t];
  }
  __syncthreads();
  if (t < 64) {
    float a = c1b[t];
    for (int ci = 0; ci < 64; ci++) a += pm[ci] * c1w[t * 64 + ci];
    p1[t] = fmaxf(a, 0.f);
  }
  __syncthreads();
  if (t < N) {
    float a2 = c2b[t];
    for (int ci = 0; ci < 64; ci++) a2 += p1[ci] * c2w[t * 64 + ci];
    p2[t] = a2;
  }
  __syncthreads();
  float m = -1e30f;
  for (int n = 0; n < N; n++) m = fmaxf(m, p2[n]);
  float ev[N], s = 0.f;
  for (int n = 0; n < N; n++) { ev[n] = expf(p2[n] - m); s += ev[n]; }
  float inv = 1.f / s;
  for (int idx = t; idx < 4096; idx += 256) {
    int j = idx & 7, lane = (idx >> 3) & 63, cf = (idx >> 9) & 3, s2 = idx >> 11;
    int k = (s2 << 5) + ((lane >> 4) << 3) + j;
    int l = (cf << 4) + (lane & 15);
    float acc = 0.f;
    for (int n = 0; n < N; n++) acc += ev[n] * inv * basep[n * 4096 + k * 64 + l];
    wmf[(size_t)b * 4096 + idx] = f2bf(acc);
  }
}

__global__ void zero_k(float* p, int n) {
  int i = blockIdx.x * 256 + threadIdx.x;
  if (i < n) p[i] = 0.f;
}

extern "C" void kernel_launch(void* const* d_in, const int* in_sizes, int n_in,
                              void* d_out, int out_size, void* d_ws, size_t ws_size,
                              hipStream_t stream) {
  const float* x       = (const float*)d_in[0];
  const float* ln_g    = (const float*)d_in[1];
  const float* ln_b    = (const float*)d_in[2];
  const float* conv3_w = (const float*)d_in[3];
  const float* conv3_b = (const float*)d_in[4];
  const float* dw_w    = (const float*)d_in[5];
  const float* dw_b    = (const float*)d_in[6];
  const float* c1_w    = (const float*)d_in[7];
  const float* c1_b    = (const float*)d_in[8];
  const float* c2_w    = (const float*)d_in[9];
  const float* c2_b    = (const float*)d_in[10];
  const float* basep   = (const float*)d_in[11];
  const float* up_w    = (const float*)d_in[12];
  const float* up_b    = (const float*)d_in[13];
  const float* down_w  = (const float*)d_in[14];
  const float* down_b  = (const float*)d_in[15];
  float* out = (float*)d_out;

  char* wsb = (char*)d_ws;
  size_t big = (size_t)B * HWc * 64 * sizeof(ushort);  // 67,108,864
  ushort* bufA   = (ushort*)wsb;
  ushort* bufB   = (ushort*)(wsb + big);
  ushort* wfrags = (ushort*)(wsb + 2 * big);
  ushort* wmfrag = (ushort*)(wsb + 2 * big + 3 * 36864 * 2);
  float*  Ssum   = (float*)(wsb + 2 * big + 3 * 36864 * 2 + 8 * 4096 * 2);
  const ushort* zbuf = (const ushort*)(Ssum + 512);

  prep_w<<<54, 256, 0, stream>>>(conv3_w, up_w, down_w, wfrags);
  zero_k<<<8, 256, 0, stream>>>(Ssum, 2048);
  // 1. LN: x -> bufA (NHWC bf16)
  ln_k<<<dim3(HWc / 256, B), 256, 0, stream>>>(x, ln_g, ln_b, bufA);
  // 2. conv3 + GELU + tile-sum: bufA -> bufB (x1), Ssum
  conv_mfma<1, 0, 1><<<dim3(16, 16, B), 256, 0, stream>>>(
      bufA, wfrags + 0 * 36864, conv3_b, nullptr, bufB, nullptr, Ssum, zbuf);
  // 3. edge stats + MLP + blend: -> wmfrag
  mlp_k<<<B, 256, 0, stream>>>(bufB, Ssum, dw_w, dw_b, c1_w, c1_b, c2_w, c2_b,
                               basep, wmfrag);
  // 4. fused up conv + mix: bufB -> bufA (xm2, NHWC bf16)
  upmix_mfma<<<dim3(16, 16, B), 256, 0, stream>>>(
      bufB, wfrags + 1 * 36864, up_b, wmfrag, bufA, zbuf);
  // 5. down conv + residual: bufA -> out (NCHW fp32)
  conv_mfma<0, 1, 0><<<dim3(16, 16, B), 256, 0, stream>>>(
      bufA, wfrags + 2 * 36864, down_b, x, nullptr, out, Ssum, zbuf);
}